// Round 5
// baseline (1475.428 us; speedup 1.0000x reference)
//
#include <hip/hip_runtime.h>

// ---------------------------------------------------------------------------
// SublayerConnection: MHA + residual/LN + FF + residual/LN
// B=4 S=2048 D=1024 H=16 Dk=64 Dff=4096. Inputs fp32-or-bf16 (runtime detect).
// Round 5: 48.1MiB overlay layout (proven ws floor 52.0MiB). Big GEMMs:
// QKV M=4096x2 (z=3 co-dispatch), Wo full-M, FF quarters with LN folded into
// W1T/S1/T1 (epilogue-only), FF2 64x128-tile with fused +bf2+x in-place.
// Mask packed to bits (ballot). fp32 accumulation everywhere.
// ---------------------------------------------------------------------------

#define DM   1024
#define DFF  4096
#define SEQ  2048

typedef unsigned short u16;
typedef short          sx8  __attribute__((ext_vector_type(8)));
typedef unsigned short ushx8 __attribute__((ext_vector_type(8)));
typedef unsigned short ushx4 __attribute__((ext_vector_type(4)));
typedef float          fx4  __attribute__((ext_vector_type(4)));
typedef unsigned int   uix4 __attribute__((ext_vector_type(4)));

__device__ __forceinline__ void async16(const void* g, void* l) {
  __builtin_amdgcn_global_load_lds((__attribute__((address_space(1))) void*)g,
                                   (__attribute__((address_space(3))) void*)l,
                                   16, 0, 0);
}
__device__ __forceinline__ float b2f(u16 u) {
  union { unsigned int i; float f; } v; v.i = ((unsigned int)u) << 16; return v.f;
}
__device__ __forceinline__ u16 f2b(float f) {
  union { float f; unsigned int i; } v; v.f = f;
  unsigned int r = v.i + 0x7fffu + ((v.i >> 16) & 1u);
  return (u16)(r >> 16);
}
__device__ __forceinline__ ushx8 ld8(const void* p, long idx, bool f32) {
  if (f32) {
    const float* s = (const float*)p + idx;
    fx4 a = *(const fx4*)s, b = *(const fx4*)(s + 4);
    ushx8 r;
    r[0] = f2b(a[0]); r[1] = f2b(a[1]); r[2] = f2b(a[2]); r[3] = f2b(a[3]);
    r[4] = f2b(b[0]); r[5] = f2b(b[1]); r[6] = f2b(b[2]); r[7] = f2b(b[3]);
    return r;
  }
  return *(const ushx8*)((const u16*)p + idx);
}
__device__ __forceinline__ void ld4f(const void* p, long idx, bool f32, float* o) {
  if (f32) {
    fx4 a = *(const fx4*)((const float*)p + idx);
    o[0] = a[0]; o[1] = a[1]; o[2] = a[2]; o[3] = a[3];
  } else {
    ushx4 a = *(const ushx4*)((const u16*)p + idx);
    o[0] = b2f(a[0]); o[1] = b2f(a[1]); o[2] = b2f(a[2]); o[3] = b2f(a[3]);
  }
}
__device__ __forceinline__ float ldf(const void* p, long idx, bool f32) {
  return f32 ? ((const float*)p)[idx] : b2f(((const u16*)p)[idx]);
}

// ---------------------------------------------------------------------------
__global__ void detect_kernel(const void* q, int* flags) {
  int lane = threadIdx.x;
  u16 v = ((const u16*)q)[lane << 1];
  int e = (v >> 7) & 0xff;
  int pl = (e >= 0x60 && e <= 0x8c) ? 1 : 0;
  unsigned long long m = __ballot(pl);
  if (lane == 0) { flags[0] = (__popcll(m) >= 40) ? 0 : 1; }
}

// Convert g1,b1,bf2,bo (1024 each) to bf16 in R0.
__global__ __launch_bounds__(256)
void conv_params(const void* g1, const void* b1, const void* bf2, const void* bo,
                 u16* g1b, u16* b1b, u16* bf2b, u16* bob, const int* f_p) {
  const bool f = (*f_p != 0);
  int i = blockIdx.x * 256 + threadIdx.x;   // 0..4095
  int which = i >> 10, j = i & 1023;
  const void* s = which == 0 ? g1 : (which == 1 ? b1 : (which == 2 ? bf2 : bo));
  u16* d = which == 0 ? g1b : (which == 1 ? b1b : (which == 2 ? bf2b : bob));
  d[j] = f2b(ldf(s, j, f));
}

// S1[n] = sum_k gff[k]*W1[k][n];  T1[n] = sum_k bff[k]*W1[k][n] + bf1[n]
__global__ __launch_bounds__(256)
void s1t1_kernel(const void* W1, const void* gff, const void* bff, const void* bf1,
                 float* S1, float* T1, const int* f_p) {
  const bool f = (*f_p != 0);
  int n = blockIdx.x * 256 + threadIdx.x;   // 0..4095
  float s = 0.f, t = 0.f;
  for (int k = 0; k < DM; ++k) {
    float w = ldf(W1, (long)k * DFF + n, f);
    s += ldf(gff, k, f) * w;
    t += ldf(bff, k, f) * w;
  }
  S1[n] = s;
  T1[n] = t + ldf(bf1, n, f);
}

// Pack mask (int32, B*S*S) into bits via ballot. 262144 u64 words.
__global__ __launch_bounds__(256)
void mask_pack(const int* __restrict__ mask, unsigned long long* __restrict__ mb) {
  const int lane = threadIdx.x & 63, w = threadIdx.x >> 6;
  const int wgid = blockIdx.x * 4 + w;      // 0..1023
  for (int i = 0; i < 256; ++i) {
    long p = (long)wgid * 256 + i;
    int m = mask[(p << 6) + lane];
    unsigned long long bm = __ballot(m != 0);
    if (lane == 0) mb[p] = bm;
  }
}

// transpose with optional per-input-row scale: out[c*R+r] = in[r*C+c]*sc[r]
__global__ __launch_bounds__(256)
void transpose_scale(const void* __restrict__ in, u16* __restrict__ out,
                     int R, int C, const void* sc, const int* f_p) {
  __shared__ u16 tile[64][68];
  const bool f = (*f_p != 0);
  const int r0 = blockIdx.y << 6, c0 = blockIdx.x << 6;
  const int t = threadIdx.x;
#pragma unroll
  for (int it = 0; it < 4; ++it) {
    int j = (it << 8) + t;
    int rr = j >> 4, cc4 = (j & 15) << 2;
    float v[4];
    ld4f(in, (long)(r0 + rr) * C + c0 + cc4, f, v);
    float s = sc ? ldf(sc, r0 + rr, f) : 1.f;
#pragma unroll
    for (int q = 0; q < 4; ++q) tile[rr][cc4 + q] = f2b(v[q] * s);
  }
  __syncthreads();
#pragma unroll
  for (int it = 0; it < 4; ++it) {
    int j = (it << 8) + t;
    int cc = j >> 4, rr4 = (j & 15) << 2;
    ushx4 v;
    v[0] = tile[rr4 + 0][cc]; v[1] = tile[rr4 + 1][cc];
    v[2] = tile[rr4 + 2][cc]; v[3] = tile[rr4 + 3][cc];
    *(ushx4*)&out[(size_t)(c0 + cc) * R + r0 + rr4] = v;
  }
}

// ---------------------------------------------------------------------------
// Unified NT GEMM. C = A@B^T with epilogues.
// BM_ in {128,64} (BN fixed 128). EPI: 0=+bias, 1=LN1-fold(+S1/T1, rs,mu),
// 2=+bias+dest (in-place residual). AFLAG/BFLAG: operand dtype via flag (ld8
// staging) vs pure bf16 (async16). z=blockIdx.y selects among 3 A/B/C slots.
// ---------------------------------------------------------------------------
template<int BM_, int EPI, bool RELU, bool AFLAG, bool BFLAG>
__global__ __launch_bounds__(256)
void gemm(const void* a0, const void* a1, const void* a2, long aoff,
          const void* b0, const void* b1, const void* b2,
          const u16* __restrict__ bias, u16* __restrict__ C, long csec,
          int M, int N, int K, int ldc,
          const float* __restrict__ mu2, const float* __restrict__ rs2,
          const float* __restrict__ S1, const float* __restrict__ T1,
          const int* f_p) {
  __shared__ __align__(16) u16 sA[BM_ * 64];
  __shared__ __align__(16) u16 sB[128 * 64];
  const int z = blockIdx.y;
  const void* A = z == 0 ? a0 : (z == 1 ? a1 : a2);
  const void* B = z == 0 ? b0 : (z == 1 ? b1 : b2);
  u16* Cz = C + (long)z * csec;
  const bool fl = (AFLAG || BFLAG) ? (*f_p != 0) : false;
  const int t = threadIdx.x;
  const int lane = t & 63, w = t >> 6;
  const int lm = lane & 15, lg = lane >> 4;
  const int ntil = N >> 7;
  const int m0 = (blockIdx.x / ntil) * BM_;
  const int n0 = (blockIdx.x % ntil) << 7;
  constexpr int ITI = BM_ / 32;               // i-tiles per wave (4 or 2)
  const int wm = (w & 1) * (BM_ / 2), wn = (w >> 1) << 6;

  fx4 acc[ITI][4];
#pragma unroll
  for (int i = 0; i < ITI; ++i)
#pragma unroll
    for (int j = 0; j < 4; ++j) acc[i][j] = (fx4){0.f, 0.f, 0.f, 0.f};

  for (int kt = 0; kt < K; kt += 64) {
    __syncthreads();
#pragma unroll
    for (int it = 0; it < BM_ / 32; ++it) {
      int ci = (it << 8) + t;
      int r = ci >> 3, cs = (ci & 7) ^ (r & 7);
      long gi = aoff + (long)(m0 + r) * K + kt + (cs << 3);
      if (AFLAG) { *(ushx8*)&sA[ci << 3] = ld8(A, gi, fl); }
      else       { async16(&((const u16*)A)[gi], &sA[ci << 3]); }
    }
#pragma unroll
    for (int it = 0; it < 4; ++it) {
      int ci = (it << 8) + t;
      int r = ci >> 3, cs = (ci & 7) ^ (r & 7);
      long gi = (long)(n0 + r) * K + kt + (cs << 3);
      if (BFLAG) { *(ushx8*)&sB[ci << 3] = ld8(B, gi, fl); }
      else       { async16(&((const u16*)B)[gi], &sB[ci << 3]); }
    }
    __syncthreads();
#pragma unroll
    for (int s = 0; s < 2; ++s) {
      const int g = (s << 2) + lg;
      sx8 afr[ITI], bfr[4];
#pragma unroll
      for (int i = 0; i < ITI; ++i) {
        int ra = wm + (i << 4) + lm;
        afr[i] = *(const sx8*)&sA[ra * 64 + ((g ^ (ra & 7)) << 3)];
      }
#pragma unroll
      for (int j = 0; j < 4; ++j) {
        int rb = wn + (j << 4) + lm;
        bfr[j] = *(const sx8*)&sB[rb * 64 + ((g ^ (rb & 7)) << 3)];
      }
#pragma unroll
      for (int i = 0; i < ITI; ++i)
#pragma unroll
        for (int j = 0; j < 4; ++j)
          acc[i][j] = __builtin_amdgcn_mfma_f32_16x16x32_bf16(afr[i], bfr[j], acc[i][j], 0, 0, 0);
    }
  }

#pragma unroll
  for (int j = 0; j < 4; ++j) {
    const int col = n0 + wn + (j << 4) + lm;
    float bv = 0.f, s1 = 0.f, t1 = 0.f;
    if (EPI == 0 || EPI == 2) { if (bias) bv = b2f(bias[col]); }
    if (EPI == 1) { s1 = S1[col]; t1 = T1[col]; }
#pragma unroll
    for (int i = 0; i < ITI; ++i) {
      const int row0 = m0 + wm + (i << 4) + (lg << 2);
#pragma unroll
      for (int r = 0; r < 4; ++r) {
        const int row = row0 + r;
        float v = acc[i][j][r];
        if (EPI == 0) v += bv;
        if (EPI == 1) {
          float rs = rs2[row], mu = mu2[row];
          v = rs * v - rs * mu * s1 + t1;
        }
        if (EPI == 2) v += bv + b2f(Cz[(size_t)row * ldc + col]);
        if (RELU) v = fmaxf(v, 0.f);
        Cz[(size_t)row * ldc + col] = f2b(v);
      }
    }
  }
}

// ---------------------------------------------------------------------------
// Flash attention, 2 batches per dispatch (grid 1024). Sections [4096,1024].
// Mask via packed bits (broadcast uint4 loads).
// ---------------------------------------------------------------------------
__global__ __launch_bounds__(256)
void attn_kernel(const u16* __restrict__ qsec, const u16* __restrict__ ksec,
                 const u16* __restrict__ vsec, const unsigned int* __restrict__ mb,
                 u16* __restrict__ ctx) {
  __shared__ __align__(16) u16 sQ[64 * 64];
  __shared__ __align__(16) u16 sK[128 * 64];
  __shared__ __align__(16) u16 sVt[64 * 136];
  __shared__ __align__(16) u16 sP[4][16 * 136];

  const int id = blockIdx.x;
  const int bl = id >> 9;                       // batch-in-group
  const int h  = (id >> 5) & 15;
  const int q0 = (id & 31) << 6;
  const int t = threadIdx.x, lane = t & 63, w = t >> 6;
  const int hoff = h << 6;
  const int lm = lane & 15, lg = lane >> 4;
  const size_t bo = (size_t)bl * SEQ * DM;
  const u16* qp = qsec + bo;
  const u16* kp = ksec + bo;
  const u16* vp = vsec + bo;
  const unsigned int* mbb = mb + (size_t)bl * SEQ * 64;
  u16* cout = ctx + bo;

#pragma unroll
  for (int it = 0; it < 2; ++it) {
    int ci = (it << 8) + t;
    int r = ci >> 3, cs = (ci & 7) ^ (r & 7);
    ushx8 v = *(const ushx8*)&qp[((size_t)(q0 + r) << 10) + hoff + (cs << 3)];
    *(ushx8*)&sQ[ci << 3] = v;
  }

  fx4 o[4];
  float m_prev[4], lsum[4];
#pragma unroll
  for (int i = 0; i < 4; ++i) { o[i] = (fx4){0.f, 0.f, 0.f, 0.f}; m_prev[i] = -1e30f; lsum[i] = 0.f; }

  for (int kt = 0; kt < 16; ++kt) {
    const int k0 = kt << 7;
    __syncthreads();
#pragma unroll
    for (int it = 0; it < 4; ++it) {
      int ci = (it << 8) + t;
      int r = ci >> 3, cs = (ci & 7) ^ (r & 7);
      ushx8 v = *(const ushx8*)&kp[((size_t)(k0 + r) << 10) + hoff + (cs << 3)];
      *(ushx8*)&sK[ci << 3] = v;
    }
    {
      const int key = t >> 1;
#pragma unroll
      for (int it = 0; it < 4; ++it) {
        int dc = (t & 1) + (it << 1);
        ushx8 vv = *(const ushx8*)&vp[((size_t)(k0 + key) << 10) + hoff + (dc << 3)];
#pragma unroll
        for (int j = 0; j < 8; ++j)
          sVt[((dc << 3) + j) * 136 + key] = vv[j];
      }
    }
    __syncthreads();

    fx4 sc[8];
#pragma unroll
    for (int nt = 0; nt < 8; ++nt) sc[nt] = (fx4){0.f, 0.f, 0.f, 0.f};
#pragma unroll
    for (int s = 0; s < 2; ++s) {
      const int g = (s << 2) + lg;
      const int rowq = (w << 4) + lm;
      sx8 aq = *(const sx8*)&sQ[rowq * 64 + ((g ^ (rowq & 7)) << 3)];
#pragma unroll
      for (int nt = 0; nt < 8; ++nt) {
        int rk = (nt << 4) + lm;
        sx8 bk = *(const sx8*)&sK[rk * 64 + ((g ^ (rk & 7)) << 3)];
        sc[nt] = __builtin_amdgcn_mfma_f32_16x16x32_bf16(aq, bk, sc[nt], 0, 0, 0);
      }
    }

    // mask bits: per row r one broadcast uint4 covering cols [k0, k0+128)
    uix4 mw[4];
#pragma unroll
    for (int r = 0; r < 4; ++r) {
      const int rowl = q0 + (w << 4) + (lg << 2) + r;
      mw[r] = *(const uix4*)&mbb[((size_t)rowl << 6) + (kt << 2)];
    }

    float pmat[8][4];
    float tmax[4] = {-1e30f, -1e30f, -1e30f, -1e30f};
#pragma unroll
    for (int nt = 0; nt < 8; ++nt) {
#pragma unroll
      for (int r = 0; r < 4; ++r) {
        float v = sc[nt][r] * 0.125f;
        unsigned int bit = (mw[r][nt >> 1] >> (((nt & 1) << 4) + lm)) & 1u;
        if (!bit) v = -1e9f;
        pmat[nt][r] = v;
        tmax[r] = fmaxf(tmax[r], v);
      }
    }
#pragma unroll
    for (int r = 0; r < 4; ++r)
#pragma unroll
      for (int off = 1; off < 16; off <<= 1)
        tmax[r] = fmaxf(tmax[r], __shfl_xor(tmax[r], off));

    float alpha[4], rsum[4] = {0.f, 0.f, 0.f, 0.f};
#pragma unroll
    for (int r = 0; r < 4; ++r) {
      float mn = fmaxf(m_prev[r], tmax[r]);
      alpha[r] = __expf(m_prev[r] - mn);
      m_prev[r] = mn;
    }
#pragma unroll
    for (int nt = 0; nt < 8; ++nt)
#pragma unroll
      for (int r = 0; r < 4; ++r) {
        float pv = __expf(pmat[nt][r] - m_prev[r]);
        pmat[nt][r] = pv;
        rsum[r] += pv;
      }
#pragma unroll
    for (int r = 0; r < 4; ++r) {
#pragma unroll
      for (int off = 1; off < 16; off <<= 1)
        rsum[r] += __shfl_xor(rsum[r], off);
      lsum[r] = lsum[r] * alpha[r] + rsum[r];
    }
#pragma unroll
    for (int ot = 0; ot < 4; ++ot)
#pragma unroll
      for (int r = 0; r < 4; ++r)
        o[ot][r] *= alpha[r];

    u16* pw = &sP[w][0];
#pragma unroll
    for (int nt = 0; nt < 8; ++nt)
#pragma unroll
      for (int r = 0; r < 4; ++r)
        pw[((lg << 2) + r) * 136 + (nt << 4) + lm] = f2b(pmat[nt][r]);

#pragma unroll
    for (int ks = 0; ks < 4; ++ks) {
      sx8 ap = *(const sx8*)&pw[lm * 136 + (ks << 5) + (lg << 3)];
#pragma unroll
      for (int ot = 0; ot < 4; ++ot) {
        int d = (ot << 4) + lm;
        sx8 bv = *(const sx8*)&sVt[d * 136 + (ks << 5) + (lg << 3)];
        o[ot] = __builtin_amdgcn_mfma_f32_16x16x32_bf16(ap, bv, o[ot], 0, 0, 0);
      }
    }
  }

  float inv[4];
#pragma unroll
  for (int r = 0; r < 4; ++r) inv[r] = (lsum[r] > 0.f) ? 1.f / lsum[r] : 0.f;
#pragma unroll
  for (int ot = 0; ot < 4; ++ot)
#pragma unroll
    for (int r = 0; r < 4; ++r) {
      const int rowg = q0 + (w << 4) + (lg << 2) + r;
      const int col = hoff + (ot << 4) + lm;
      cout[((size_t)rowg << 10) + col] = f2b(o[ot][r] * inv[r]);
    }
}

// ---------------------------------------------------------------------------
// LN1 in-place + LN2 stats: x = LN(ao + query; g1b,b1b) written over ao;
// mu2/rs2 of x (f32, pre-rounding) stored per row.
// ---------------------------------------------------------------------------
__global__ __launch_bounds__(256)
void ln_dual_v2(u16* __restrict__ a, const void* __restrict__ res,
                const u16* __restrict__ g1b, const u16* __restrict__ b1b,
                float* __restrict__ mu2, float* __restrict__ rs2, const int* f_p) {
  __shared__ float red[8];
  const bool f = (*f_p != 0);
  const int row = blockIdx.x, t = threadIdx.x;
  const int lane = t & 63, w = t >> 6;
  const size_t base = (size_t)row << 10;
  const int c = t << 2;

  ushx4 a4 = *(const ushx4*)(a + base + c);
  float rv[4];
  ld4f(res, (long)base + c, f, rv);
  float v[4], s = 0.f, ss = 0.f;
#pragma unroll
  for (int j = 0; j < 4; ++j) { v[j] = b2f(a4[j]) + rv[j]; s += v[j]; ss += v[j] * v[j]; }
#pragma unroll
  for (int off = 32; off > 0; off >>= 1) { s += __shfl_xor(s, off); ss += __shfl_xor(ss, off); }
  if (lane == 0) { red[w] = s; red[4 + w] = ss; }
  __syncthreads();
  s = red[0] + red[1] + red[2] + red[3];
  ss = red[4] + red[5] + red[6] + red[7];
  float mu = s * (1.f / 1024.f);
  float rstd = rsqrtf(fmaxf(ss * (1.f / 1024.f) - mu * mu, 0.f) + 1e-5f);

  ushx4 g4 = *(const ushx4*)(g1b + c), b4 = *(const ushx4*)(b1b + c);
  float x[4], s2 = 0.f, ss2 = 0.f;
  ushx4 xo4;
#pragma unroll
  for (int j = 0; j < 4; ++j) {
    x[j] = (v[j] - mu) * rstd * b2f(g4[j]) + b2f(b4[j]);
    xo4[j] = f2b(x[j]);
    s2 += x[j]; ss2 += x[j] * x[j];
  }
  *(ushx4*)(a + base + c) = xo4;   // in-place
#pragma unroll
  for (int off = 32; off > 0; off >>= 1) { s2 += __shfl_xor(s2, off); ss2 += __shfl_xor(ss2, off); }
  __syncthreads();
  if (lane == 0) { red[w] = s2; red[4 + w] = ss2; }
  __syncthreads();
  if (t == 0) {
    s2 = red[0] + red[1] + red[2] + red[3];
    ss2 = red[4] + red[5] + red[6] + red[7];
    float m2 = s2 * (1.f / 1024.f);
    mu2[row] = m2;
    rs2[row] = rsqrtf(fmaxf(ss2 * (1.f / 1024.f) - m2 * m2, 0.f) + 1e-5f);
  }
}

// Final LN: out = LN(z; g2,b2). z already holds ff + x.
__global__ __launch_bounds__(256)
void ln_final2(const u16* __restrict__ z, const void* __restrict__ g,
               const void* __restrict__ bb, void* __restrict__ out, const int* f_p) {
  __shared__ float red[8];
  const bool f = (*f_p != 0);
  const int row = blockIdx.x, t = threadIdx.x;
  const int lane = t & 63, w = t >> 6;
  const size_t base = (size_t)row << 10;
  const int c = t << 2;

  ushx4 a4 = *(const ushx4*)(z + base + c);
  float v[4], s = 0.f, ss = 0.f;
#pragma unroll
  for (int j = 0; j < 4; ++j) { v[j] = b2f(a4[j]); s += v[j]; ss += v[j] * v[j]; }
#pragma unroll
  for (int off = 32; off > 0; off >>= 1) { s += __shfl_xor(s, off); ss += __shfl_xor(ss, off); }
  if (lane == 0) { red[w] = s; red[4 + w] = ss; }
  __syncthreads();
  s = red[0] + red[1] + red[2] + red[3];
  ss = red[4] + red[5] + red[6] + red[7];
  float mu = s * (1.f / 1024.f);
  float rstd = rsqrtf(fmaxf(ss * (1.f / 1024.f) - mu * mu, 0.f) + 1e-5f);

  float g4[4], b4[4];
  ld4f(g, c, f, g4); ld4f(bb, c, f, b4);
  if (f) {
    fx4 o4;
#pragma unroll
    for (int j = 0; j < 4; ++j) o4[j] = (v[j] - mu) * rstd * g4[j] + b4[j];
    *(fx4*)((float*)out + base + c) = o4;
  } else {
    ushx4 o4;
#pragma unroll
    for (int j = 0; j < 4; ++j) o4[j] = f2b((v[j] - mu) * rstd * g4[j] + b4[j]);
    *(ushx4*)((u16*)out + base + c) = o4;
  }
}

// ---------------------------------------------------------------------------
extern "C" void kernel_launch(void* const* d_in, const int* in_sizes, int n_in,
                              void* d_out, int out_size, void* d_ws, size_t ws_size,
                              hipStream_t stream) {
  (void)in_sizes; (void)n_in; (void)out_size; (void)ws_size;
  const void* query = d_in[0];
  const void* keyi  = d_in[1];
  const void* value = d_in[2];
  const int*  mask  = (const int*)d_in[3];
  const void* Wq = d_in[4];
  const void* Wk = d_in[5];
  const void* Wv = d_in[6];
  const void* Wo = d_in[7];
  const void* bo = d_in[8];
  const void* g1 = d_in[9];
  const void* b1 = d_in[10];
  const void* g2 = d_in[11];
  const void* b2 = d_in[12];
  const void* gff = d_in[13];
  const void* bff = d_in[14];
  const void* W1 = d_in[15];
  const void* bf1 = d_in[16];
  const void* W2 = d_in[17];
  const void* bf2 = d_in[18];

  char* p = (char*)d_ws;
  // R0 (128KiB): flags | mu2 | rs2 | S1 | T1 | g1b | b1b | bf2b | bob
  int*   flags = (int*)p;
  float* mu2  = (float*)(p + 4096);
  float* rs2  = (float*)(p + 4096 + 32768);
  float* S1   = (float*)(p + 4096 + 65536);
  float* T1   = (float*)(p + 4096 + 65536 + 16384);
  u16*   g1b  = (u16*)(p + 102400);
  u16*   b1b  = (u16*)(p + 104448);
  u16*   bf2b = (u16*)(p + 106496);
  u16*   bob  = (u16*)(p + 108544);
  const int* F = flags;

  // Overlay layout (peak 48.1 MiB; proven ws floor = 52.0 MiB):
  u16* ctx   = (u16*)(p + 131072);                     // [8192,1024]  16MiB
  u16* W1T   = ctx;                                    // after Wo: [4096,1024]
  u16* W2T   = ctx + (size_t)DFF * DM;                 //           [1024,4096]
  u16* qkv   = (u16*)(p + 131072 + 16777216);          // 2-batch q|k|v  24MiB
  u16* ao    = qkv;                                    // after attn: ao/x 16MiB
  u16* x     = qkv;
  u16* h     = qkv + (size_t)8192 * DM;                // FF scratch 16MiB
  unsigned int* maskb = (unsigned int*)(p + 131072 + 16777216 + 25165824); // 2MiB

  dim3 blk(256);
  const long SEC = (long)4096 * DM;                    // qkv section elems

  detect_kernel<<<1, 64, 0, stream>>>(query, flags);
  conv_params<<<16, blk, 0, stream>>>(g1, b1, bf2, bo, g1b, b1b, bf2b, bob, F);
  mask_pack<<<256, blk, 0, stream>>>(mask, (unsigned long long*)maskb);
  s1t1_kernel<<<16, blk, 0, stream>>>(W1, gff, bff, bf1, S1, T1, F);

  for (int g = 0; g < 2; ++g) {
    const long aoff = (long)g * 4096 * DM;
    // QKV co-dispatch: z selects (query,Wq)/(key,Wk)/(value,Wv)
    gemm<128, 0, false, true, true><<<dim3(32 * 8, 3), blk, 0, stream>>>(
        query, keyi, value, aoff, Wq, Wk, Wv, nullptr,
        qkv, SEC, 4096, DM, DM, DM, nullptr, nullptr, nullptr, nullptr, F);
    attn_kernel<<<dim3(1024), blk, 0, stream>>>(
        qkv, qkv + SEC, qkv + 2 * SEC,
        maskb + (size_t)g * 2 * SEQ * 64, ctx + aoff);
  }

  // Wo projection, full M: ao overlays dead qkv
  gemm<128, 0, false, false, true><<<dim3(64 * 8, 1), blk, 0, stream>>>(
      ctx, ctx, ctx, 0, Wo, Wo, Wo, bob,
      ao, 0, 8192, DM, DM, DM, nullptr, nullptr, nullptr, nullptr, F);

  // x = LN(ao + query) in-place; LN2 stats saved
  ln_dual_v2<<<dim3(8192), blk, 0, stream>>>(ao, query, g1b, b1b, mu2, rs2, F);

  // ctx dead: build W1T (scaled by gff) and W2T in its place
  transpose_scale<<<dim3(DFF / 64, DM / 64), blk, 0, stream>>>(W1, W1T, DM, DFF, gff, F);
  transpose_scale<<<dim3(DM / 64, DFF / 64), blk, 0, stream>>>(W2, W2T, DFF, DM, nullptr, F);

  // FF quarters: h = relu(LN-folded x@W1g^T); z = h@W2T^T + bf2 + x (in-place)
  for (int q = 0; q < 4; ++q) {
    u16* xq = x + (long)q * 2048 * DM;
    gemm<128, 1, true, false, false><<<dim3(16 * 32, 1), blk, 0, stream>>>(
        xq, xq, xq, 0, W1T, W1T, W1T, nullptr,
        h, 0, 2048, DFF, DM, DFF, mu2 + q * 2048, rs2 + q * 2048, S1, T1, F);
    gemm<64, 2, false, false, false><<<dim3(32 * 8, 1), blk, 0, stream>>>(
        h, h, h, 0, W2T, W2T, W2T, bf2b,
        xq, 0, 2048, DM, DFF, DM, nullptr, nullptr, nullptr, nullptr, F);
  }

  ln_final2<<<dim3(8192), blk, 0, stream>>>(x, g2, b2, d_out, F);
}

// Round 6
// 1118.283 us; speedup vs baseline: 1.3194x; 1.3194x over previous
//
#include <hip/hip_runtime.h>

// ---------------------------------------------------------------------------
// SublayerConnection: MHA + residual/LN + FF + residual/LN
// B=4 S=2048 D=1024 H=16 Dk=64 Dff=4096. Inputs fp32-or-bf16 (runtime detect).
// Round 6: round-5 structure with the two serial helper kernels parallelized
// (s1t1: 16 -> 512 blocks w/ atomics; mask_pack: 256 -> 2048 blocks).
// ---------------------------------------------------------------------------

#define DM   1024
#define DFF  4096
#define SEQ  2048

typedef unsigned short u16;
typedef short          sx8  __attribute__((ext_vector_type(8)));
typedef unsigned short ushx8 __attribute__((ext_vector_type(8)));
typedef unsigned short ushx4 __attribute__((ext_vector_type(4)));
typedef float          fx4  __attribute__((ext_vector_type(4)));
typedef unsigned int   uix4 __attribute__((ext_vector_type(4)));

__device__ __forceinline__ void async16(const void* g, void* l) {
  __builtin_amdgcn_global_load_lds((__attribute__((address_space(1))) void*)g,
                                   (__attribute__((address_space(3))) void*)l,
                                   16, 0, 0);
}
__device__ __forceinline__ float b2f(u16 u) {
  union { unsigned int i; float f; } v; v.i = ((unsigned int)u) << 16; return v.f;
}
__device__ __forceinline__ u16 f2b(float f) {
  union { float f; unsigned int i; } v; v.f = f;
  unsigned int r = v.i + 0x7fffu + ((v.i >> 16) & 1u);
  return (u16)(r >> 16);
}
__device__ __forceinline__ ushx8 ld8(const void* p, long idx, bool f32) {
  if (f32) {
    const float* s = (const float*)p + idx;
    fx4 a = *(const fx4*)s, b = *(const fx4*)(s + 4);
    ushx8 r;
    r[0] = f2b(a[0]); r[1] = f2b(a[1]); r[2] = f2b(a[2]); r[3] = f2b(a[3]);
    r[4] = f2b(b[0]); r[5] = f2b(b[1]); r[6] = f2b(b[2]); r[7] = f2b(b[3]);
    return r;
  }
  return *(const ushx8*)((const u16*)p + idx);
}
__device__ __forceinline__ void ld4f(const void* p, long idx, bool f32, float* o) {
  if (f32) {
    fx4 a = *(const fx4*)((const float*)p + idx);
    o[0] = a[0]; o[1] = a[1]; o[2] = a[2]; o[3] = a[3];
  } else {
    ushx4 a = *(const ushx4*)((const u16*)p + idx);
    o[0] = b2f(a[0]); o[1] = b2f(a[1]); o[2] = b2f(a[2]); o[3] = b2f(a[3]);
  }
}
__device__ __forceinline__ float ldf(const void* p, long idx, bool f32) {
  return f32 ? ((const float*)p)[idx] : b2f(((const u16*)p)[idx]);
}

// ---------------------------------------------------------------------------
__global__ void detect_kernel(const void* q, int* flags) {
  int lane = threadIdx.x;
  u16 v = ((const u16*)q)[lane << 1];
  int e = (v >> 7) & 0xff;
  int pl = (e >= 0x60 && e <= 0x8c) ? 1 : 0;
  unsigned long long m = __ballot(pl);
  if (lane == 0) { flags[0] = (__popcll(m) >= 40) ? 0 : 1; }
}

// Convert g1,b1,bf2,bo (1024 each) to bf16 in R0.
__global__ __launch_bounds__(256)
void conv_params(const void* g1, const void* b1, const void* bf2, const void* bo,
                 u16* g1b, u16* b1b, u16* bf2b, u16* bob, const int* f_p) {
  const bool f = (*f_p != 0);
  int i = blockIdx.x * 256 + threadIdx.x;   // 0..4095
  int which = i >> 10, j = i & 1023;
  const void* s = which == 0 ? g1 : (which == 1 ? b1 : (which == 2 ? bf2 : bo));
  u16* d = which == 0 ? g1b : (which == 1 ? b1b : (which == 2 ? bf2b : bob));
  d[j] = f2b(ldf(s, j, f));
}

// S1/T1: init then parallel accumulate.
// S1[n] = sum_k gff[k]*W1[k][n];  T1[n] = sum_k bff[k]*W1[k][n] + bf1[n]
__global__ __launch_bounds__(256)
void s1t1_init(const void* bf1, float* S1, float* T1, const int* f_p) {
  const bool f = (*f_p != 0);
  int n = blockIdx.x * 256 + threadIdx.x;   // 0..4095
  S1[n] = 0.f;
  T1[n] = ldf(bf1, n, f);
}
__global__ __launch_bounds__(256)
void s1t1_acc(const void* W1, const void* gff, const void* bff,
              float* S1, float* T1, const int* f_p) {
  const bool f = (*f_p != 0);
  const int strip = blockIdx.x & 15;        // n-strip (16 x 256 cols)
  const int kc = blockIdx.x >> 4;           // k-chunk (32 x 32 rows)
  const int n = (strip << 8) + threadIdx.x;
  const int k0 = kc << 5;
  float s = 0.f, t = 0.f;
#pragma unroll 4
  for (int k = k0; k < k0 + 32; ++k) {
    float w = ldf(W1, (long)k * DFF + n, f);
    s += ldf(gff, k, f) * w;
    t += ldf(bff, k, f) * w;
  }
  atomicAdd(&S1[n], s);
  atomicAdd(&T1[n], t);
}

// Pack mask (int32, B*S*S) into bits via ballot. 262144 u64 words.
// 2048 blocks x 4 waves; each wave does 32 independent ballot-words.
__global__ __launch_bounds__(256)
void mask_pack(const int* __restrict__ mask, unsigned long long* __restrict__ mb) {
  const int lane = threadIdx.x & 63, w = threadIdx.x >> 6;
  const long wave = (long)blockIdx.x * 4 + w;   // 0..8191
#pragma unroll 4
  for (int i = 0; i < 32; ++i) {
    long p = wave * 32 + i;
    unsigned long long bm = __ballot(mask[(p << 6) + lane] != 0);
    if (lane == 0) mb[p] = bm;
  }
}

// transpose with optional per-input-row scale: out[c*R+r] = in[r*C+c]*sc[r]
__global__ __launch_bounds__(256)
void transpose_scale(const void* __restrict__ in, u16* __restrict__ out,
                     int R, int C, const void* sc, const int* f_p) {
  __shared__ u16 tile[64][68];
  const bool f = (*f_p != 0);
  const int r0 = blockIdx.y << 6, c0 = blockIdx.x << 6;
  const int t = threadIdx.x;
#pragma unroll
  for (int it = 0; it < 4; ++it) {
    int j = (it << 8) + t;
    int rr = j >> 4, cc4 = (j & 15) << 2;
    float v[4];
    ld4f(in, (long)(r0 + rr) * C + c0 + cc4, f, v);
    float s = sc ? ldf(sc, r0 + rr, f) : 1.f;
#pragma unroll
    for (int q = 0; q < 4; ++q) tile[rr][cc4 + q] = f2b(v[q] * s);
  }
  __syncthreads();
#pragma unroll
  for (int it = 0; it < 4; ++it) {
    int j = (it << 8) + t;
    int cc = j >> 4, rr4 = (j & 15) << 2;
    ushx4 v;
    v[0] = tile[rr4 + 0][cc]; v[1] = tile[rr4 + 1][cc];
    v[2] = tile[rr4 + 2][cc]; v[3] = tile[rr4 + 3][cc];
    *(ushx4*)&out[(size_t)(c0 + cc) * R + r0 + rr4] = v;
  }
}

// ---------------------------------------------------------------------------
// Unified NT GEMM. C = A@B^T with epilogues.
// BM_ in {128,64} (BN fixed 128). EPI: 0=+bias, 1=LN1-fold(+S1/T1, rs,mu),
// 2=+bias+dest (in-place residual). AFLAG/BFLAG: operand dtype via flag (ld8
// staging) vs pure bf16 (async16). z=blockIdx.y selects among 3 A/B/C slots.
// ---------------------------------------------------------------------------
template<int BM_, int EPI, bool RELU, bool AFLAG, bool BFLAG>
__global__ __launch_bounds__(256)
void gemm(const void* a0, const void* a1, const void* a2, long aoff,
          const void* b0, const void* b1, const void* b2,
          const u16* __restrict__ bias, u16* __restrict__ C, long csec,
          int M, int N, int K, int ldc,
          const float* __restrict__ mu2, const float* __restrict__ rs2,
          const float* __restrict__ S1, const float* __restrict__ T1,
          const int* f_p) {
  __shared__ __align__(16) u16 sA[BM_ * 64];
  __shared__ __align__(16) u16 sB[128 * 64];
  const int z = blockIdx.y;
  const void* A = z == 0 ? a0 : (z == 1 ? a1 : a2);
  const void* B = z == 0 ? b0 : (z == 1 ? b1 : b2);
  u16* Cz = C + (long)z * csec;
  const bool fl = (AFLAG || BFLAG) ? (*f_p != 0) : false;
  const int t = threadIdx.x;
  const int lane = t & 63, w = t >> 6;
  const int lm = lane & 15, lg = lane >> 4;
  const int ntil = N >> 7;
  const int m0 = (blockIdx.x / ntil) * BM_;
  const int n0 = (blockIdx.x % ntil) << 7;
  constexpr int ITI = BM_ / 32;               // i-tiles per wave (4 or 2)
  const int wm = (w & 1) * (BM_ / 2), wn = (w >> 1) << 6;

  fx4 acc[ITI][4];
#pragma unroll
  for (int i = 0; i < ITI; ++i)
#pragma unroll
    for (int j = 0; j < 4; ++j) acc[i][j] = (fx4){0.f, 0.f, 0.f, 0.f};

  for (int kt = 0; kt < K; kt += 64) {
    __syncthreads();
#pragma unroll
    for (int it = 0; it < BM_ / 32; ++it) {
      int ci = (it << 8) + t;
      int r = ci >> 3, cs = (ci & 7) ^ (r & 7);
      long gi = aoff + (long)(m0 + r) * K + kt + (cs << 3);
      if (AFLAG) { *(ushx8*)&sA[ci << 3] = ld8(A, gi, fl); }
      else       { async16(&((const u16*)A)[gi], &sA[ci << 3]); }
    }
#pragma unroll
    for (int it = 0; it < 4; ++it) {
      int ci = (it << 8) + t;
      int r = ci >> 3, cs = (ci & 7) ^ (r & 7);
      long gi = (long)(n0 + r) * K + kt + (cs << 3);
      if (BFLAG) { *(ushx8*)&sB[ci << 3] = ld8(B, gi, fl); }
      else       { async16(&((const u16*)B)[gi], &sB[ci << 3]); }
    }
    __syncthreads();
#pragma unroll
    for (int s = 0; s < 2; ++s) {
      const int g = (s << 2) + lg;
      sx8 afr[ITI], bfr[4];
#pragma unroll
      for (int i = 0; i < ITI; ++i) {
        int ra = wm + (i << 4) + lm;
        afr[i] = *(const sx8*)&sA[ra * 64 + ((g ^ (ra & 7)) << 3)];
      }
#pragma unroll
      for (int j = 0; j < 4; ++j) {
        int rb = wn + (j << 4) + lm;
        bfr[j] = *(const sx8*)&sB[rb * 64 + ((g ^ (rb & 7)) << 3)];
      }
#pragma unroll
      for (int i = 0; i < ITI; ++i)
#pragma unroll
        for (int j = 0; j < 4; ++j)
          acc[i][j] = __builtin_amdgcn_mfma_f32_16x16x32_bf16(afr[i], bfr[j], acc[i][j], 0, 0, 0);
    }
  }

#pragma unroll
  for (int j = 0; j < 4; ++j) {
    const int col = n0 + wn + (j << 4) + lm;
    float bv = 0.f, s1 = 0.f, t1 = 0.f;
    if (EPI == 0 || EPI == 2) { if (bias) bv = b2f(bias[col]); }
    if (EPI == 1) { s1 = S1[col]; t1 = T1[col]; }
#pragma unroll
    for (int i = 0; i < ITI; ++i) {
      const int row0 = m0 + wm + (i << 4) + (lg << 2);
#pragma unroll
      for (int r = 0; r < 4; ++r) {
        const int row = row0 + r;
        float v = acc[i][j][r];
        if (EPI == 0) v += bv;
        if (EPI == 1) {
          float rs = rs2[row], mu = mu2[row];
          v = rs * v - rs * mu * s1 + t1;
        }
        if (EPI == 2) v += bv + b2f(Cz[(size_t)row * ldc + col]);
        if (RELU) v = fmaxf(v, 0.f);
        Cz[(size_t)row * ldc + col] = f2b(v);
      }
    }
  }
}

// ---------------------------------------------------------------------------
// Flash attention, 2 batches per dispatch (grid 1024). Sections [4096,1024].
// Mask via packed bits (broadcast uint4 loads).
// ---------------------------------------------------------------------------
__global__ __launch_bounds__(256)
void attn_kernel(const u16* __restrict__ qsec, const u16* __restrict__ ksec,
                 const u16* __restrict__ vsec, const unsigned int* __restrict__ mb,
                 u16* __restrict__ ctx) {
  __shared__ __align__(16) u16 sQ[64 * 64];
  __shared__ __align__(16) u16 sK[128 * 64];
  __shared__ __align__(16) u16 sVt[64 * 136];
  __shared__ __align__(16) u16 sP[4][16 * 136];

  const int id = blockIdx.x;
  const int bl = id >> 9;                       // batch-in-group
  const int h  = (id >> 5) & 15;
  const int q0 = (id & 31) << 6;
  const int t = threadIdx.x, lane = t & 63, w = t >> 6;
  const int hoff = h << 6;
  const int lm = lane & 15, lg = lane >> 4;
  const size_t bo = (size_t)bl * SEQ * DM;
  const u16* qp = qsec + bo;
  const u16* kp = ksec + bo;
  const u16* vp = vsec + bo;
  const unsigned int* mbb = mb + (size_t)bl * SEQ * 64;
  u16* cout = ctx + bo;

#pragma unroll
  for (int it = 0; it < 2; ++it) {
    int ci = (it << 8) + t;
    int r = ci >> 3, cs = (ci & 7) ^ (r & 7);
    ushx8 v = *(const ushx8*)&qp[((size_t)(q0 + r) << 10) + hoff + (cs << 3)];
    *(ushx8*)&sQ[ci << 3] = v;
  }

  fx4 o[4];
  float m_prev[4], lsum[4];
#pragma unroll
  for (int i = 0; i < 4; ++i) { o[i] = (fx4){0.f, 0.f, 0.f, 0.f}; m_prev[i] = -1e30f; lsum[i] = 0.f; }

  for (int kt = 0; kt < 16; ++kt) {
    const int k0 = kt << 7;
    __syncthreads();
#pragma unroll
    for (int it = 0; it < 4; ++it) {
      int ci = (it << 8) + t;
      int r = ci >> 3, cs = (ci & 7) ^ (r & 7);
      ushx8 v = *(const ushx8*)&kp[((size_t)(k0 + r) << 10) + hoff + (cs << 3)];
      *(ushx8*)&sK[ci << 3] = v;
    }
    {
      const int key = t >> 1;
#pragma unroll
      for (int it = 0; it < 4; ++it) {
        int dc = (t & 1) + (it << 1);
        ushx8 vv = *(const ushx8*)&vp[((size_t)(k0 + key) << 10) + hoff + (dc << 3)];
#pragma unroll
        for (int j = 0; j < 8; ++j)
          sVt[((dc << 3) + j) * 136 + key] = vv[j];
      }
    }
    __syncthreads();

    fx4 sc[8];
#pragma unroll
    for (int nt = 0; nt < 8; ++nt) sc[nt] = (fx4){0.f, 0.f, 0.f, 0.f};
#pragma unroll
    for (int s = 0; s < 2; ++s) {
      const int g = (s << 2) + lg;
      const int rowq = (w << 4) + lm;
      sx8 aq = *(const sx8*)&sQ[rowq * 64 + ((g ^ (rowq & 7)) << 3)];
#pragma unroll
      for (int nt = 0; nt < 8; ++nt) {
        int rk = (nt << 4) + lm;
        sx8 bk = *(const sx8*)&sK[rk * 64 + ((g ^ (rk & 7)) << 3)];
        sc[nt] = __builtin_amdgcn_mfma_f32_16x16x32_bf16(aq, bk, sc[nt], 0, 0, 0);
      }
    }

    // mask bits: per row r one broadcast uint4 covering cols [k0, k0+128)
    uix4 mw[4];
#pragma unroll
    for (int r = 0; r < 4; ++r) {
      const int rowl = q0 + (w << 4) + (lg << 2) + r;
      mw[r] = *(const uix4*)&mbb[((size_t)rowl << 6) + (kt << 2)];
    }

    float pmat[8][4];
    float tmax[4] = {-1e30f, -1e30f, -1e30f, -1e30f};
#pragma unroll
    for (int nt = 0; nt < 8; ++nt) {
#pragma unroll
      for (int r = 0; r < 4; ++r) {
        float v = sc[nt][r] * 0.125f;
        unsigned int bit = (mw[r][nt >> 1] >> (((nt & 1) << 4) + lm)) & 1u;
        if (!bit) v = -1e9f;
        pmat[nt][r] = v;
        tmax[r] = fmaxf(tmax[r], v);
      }
    }
#pragma unroll
    for (int r = 0; r < 4; ++r)
#pragma unroll
      for (int off = 1; off < 16; off <<= 1)
        tmax[r] = fmaxf(tmax[r], __shfl_xor(tmax[r], off));

    float alpha[4], rsum[4] = {0.f, 0.f, 0.f, 0.f};
#pragma unroll
    for (int r = 0; r < 4; ++r) {
      float mn = fmaxf(m_prev[r], tmax[r]);
      alpha[r] = __expf(m_prev[r] - mn);
      m_prev[r] = mn;
    }
#pragma unroll
    for (int nt = 0; nt < 8; ++nt)
#pragma unroll
      for (int r = 0; r < 4; ++r) {
        float pv = __expf(pmat[nt][r] - m_prev[r]);
        pmat[nt][r] = pv;
        rsum[r] += pv;
      }
#pragma unroll
    for (int r = 0; r < 4; ++r) {
#pragma unroll
      for (int off = 1; off < 16; off <<= 1)
        rsum[r] += __shfl_xor(rsum[r], off);
      lsum[r] = lsum[r] * alpha[r] + rsum[r];
    }
#pragma unroll
    for (int ot = 0; ot < 4; ++ot)
#pragma unroll
      for (int r = 0; r < 4; ++r)
        o[ot][r] *= alpha[r];

    u16* pw = &sP[w][0];
#pragma unroll
    for (int nt = 0; nt < 8; ++nt)
#pragma unroll
      for (int r = 0; r < 4; ++r)
        pw[((lg << 2) + r) * 136 + (nt << 4) + lm] = f2b(pmat[nt][r]);

#pragma unroll
    for (int ks = 0; ks < 4; ++ks) {
      sx8 ap = *(const sx8*)&pw[lm * 136 + (ks << 5) + (lg << 3)];
#pragma unroll
      for (int ot = 0; ot < 4; ++ot) {
        int d = (ot << 4) + lm;
        sx8 bv = *(const sx8*)&sVt[d * 136 + (ks << 5) + (lg << 3)];
        o[ot] = __builtin_amdgcn_mfma_f32_16x16x32_bf16(ap, bv, o[ot], 0, 0, 0);
      }
    }
  }

  float inv[4];
#pragma unroll
  for (int r = 0; r < 4; ++r) inv[r] = (lsum[r] > 0.f) ? 1.f / lsum[r] : 0.f;
#pragma unroll
  for (int ot = 0; ot < 4; ++ot)
#pragma unroll
    for (int r = 0; r < 4; ++r) {
      const int rowg = q0 + (w << 4) + (lg << 2) + r;
      const int col = hoff + (ot << 4) + lm;
      cout[((size_t)rowg << 10) + col] = f2b(o[ot][r] * inv[r]);
    }
}

// ---------------------------------------------------------------------------
// LN1 in-place + LN2 stats: x = LN(ao + query; g1b,b1b) written over ao;
// mu2/rs2 of x (f32, pre-rounding) stored per row.
// ---------------------------------------------------------------------------
__global__ __launch_bounds__(256)
void ln_dual_v2(u16* __restrict__ a, const void* __restrict__ res,
                const u16* __restrict__ g1b, const u16* __restrict__ b1b,
                float* __restrict__ mu2, float* __restrict__ rs2, const int* f_p) {
  __shared__ float red[8];
  const bool f = (*f_p != 0);
  const int row = blockIdx.x, t = threadIdx.x;
  const int lane = t & 63, w = t >> 6;
  const size_t base = (size_t)row << 10;
  const int c = t << 2;

  ushx4 a4 = *(const ushx4*)(a + base + c);
  float rv[4];
  ld4f(res, (long)base + c, f, rv);
  float v[4], s = 0.f, ss = 0.f;
#pragma unroll
  for (int j = 0; j < 4; ++j) { v[j] = b2f(a4[j]) + rv[j]; s += v[j]; ss += v[j] * v[j]; }
#pragma unroll
  for (int off = 32; off > 0; off >>= 1) { s += __shfl_xor(s, off); ss += __shfl_xor(ss, off); }
  if (lane == 0) { red[w] = s; red[4 + w] = ss; }
  __syncthreads();
  s = red[0] + red[1] + red[2] + red[3];
  ss = red[4] + red[5] + red[6] + red[7];
  float mu = s * (1.f / 1024.f);
  float rstd = rsqrtf(fmaxf(ss * (1.f / 1024.f) - mu * mu, 0.f) + 1e-5f);

  ushx4 g4 = *(const ushx4*)(g1b + c), b4 = *(const ushx4*)(b1b + c);
  float x[4], s2 = 0.f, ss2 = 0.f;
  ushx4 xo4;
#pragma unroll
  for (int j = 0; j < 4; ++j) {
    x[j] = (v[j] - mu) * rstd * b2f(g4[j]) + b2f(b4[j]);
    xo4[j] = f2b(x[j]);
    s2 += x[j]; ss2 += x[j] * x[j];
  }
  *(ushx4*)(a + base + c) = xo4;   // in-place
#pragma unroll
  for (int off = 32; off > 0; off >>= 1) { s2 += __shfl_xor(s2, off); ss2 += __shfl_xor(ss2, off); }
  __syncthreads();
  if (lane == 0) { red[w] = s2; red[4 + w] = ss2; }
  __syncthreads();
  if (t == 0) {
    s2 = red[0] + red[1] + red[2] + red[3];
    ss2 = red[4] + red[5] + red[6] + red[7];
    float m2 = s2 * (1.f / 1024.f);
    mu2[row] = m2;
    rs2[row] = rsqrtf(fmaxf(ss2 * (1.f / 1024.f) - m2 * m2, 0.f) + 1e-5f);
  }
}

// Final LN: out = LN(z; g2,b2). z already holds ff + x.
__global__ __launch_bounds__(256)
void ln_final2(const u16* __restrict__ z, const void* __restrict__ g,
               const void* __restrict__ bb, void* __restrict__ out, const int* f_p) {
  __shared__ float red[8];
  const bool f = (*f_p != 0);
  const int row = blockIdx.x, t = threadIdx.x;
  const int lane = t & 63, w = t >> 6;
  const size_t base = (size_t)row << 10;
  const int c = t << 2;

  ushx4 a4 = *(const ushx4*)(z + base + c);
  float v[4], s = 0.f, ss = 0.f;
#pragma unroll
  for (int j = 0; j < 4; ++j) { v[j] = b2f(a4[j]); s += v[j]; ss += v[j] * v[j]; }
#pragma unroll
  for (int off = 32; off > 0; off >>= 1) { s += __shfl_xor(s, off); ss += __shfl_xor(ss, off); }
  if (lane == 0) { red[w] = s; red[4 + w] = ss; }
  __syncthreads();
  s = red[0] + red[1] + red[2] + red[3];
  ss = red[4] + red[5] + red[6] + red[7];
  float mu = s * (1.f / 1024.f);
  float rstd = rsqrtf(fmaxf(ss * (1.f / 1024.f) - mu * mu, 0.f) + 1e-5f);

  float g4[4], b4[4];
  ld4f(g, c, f, g4); ld4f(bb, c, f, b4);
  if (f) {
    fx4 o4;
#pragma unroll
    for (int j = 0; j < 4; ++j) o4[j] = (v[j] - mu) * rstd * g4[j] + b4[j];
    *(fx4*)((float*)out + base + c) = o4;
  } else {
    ushx4 o4;
#pragma unroll
    for (int j = 0; j < 4; ++j) o4[j] = f2b((v[j] - mu) * rstd * g4[j] + b4[j]);
    *(ushx4*)((u16*)out + base + c) = o4;
  }
}

// ---------------------------------------------------------------------------
extern "C" void kernel_launch(void* const* d_in, const int* in_sizes, int n_in,
                              void* d_out, int out_size, void* d_ws, size_t ws_size,
                              hipStream_t stream) {
  (void)in_sizes; (void)n_in; (void)out_size; (void)ws_size;
  const void* query = d_in[0];
  const void* keyi  = d_in[1];
  const void* value = d_in[2];
  const int*  mask  = (const int*)d_in[3];
  const void* Wq = d_in[4];
  const void* Wk = d_in[5];
  const void* Wv = d_in[6];
  const void* Wo = d_in[7];
  const void* bo = d_in[8];
  const void* g1 = d_in[9];
  const void* b1 = d_in[10];
  const void* g2 = d_in[11];
  const void* b2 = d_in[12];
  const void* gff = d_in[13];
  const void* bff = d_in[14];
  const void* W1 = d_in[15];
  const void* bf1 = d_in[16];
  const void* W2 = d_in[17];
  const void* bf2 = d_in[18];

  char* p = (char*)d_ws;
  // R0 (128KiB): flags | mu2 | rs2 | S1 | T1 | g1b | b1b | bf2b | bob
  int*   flags = (int*)p;
  float* mu2  = (float*)(p + 4096);
  float* rs2  = (float*)(p + 4096 + 32768);
  float* S1   = (float*)(p + 4096 + 65536);
  float* T1   = (float*)(p + 4096 + 65536 + 16384);
  u16*   g1b  = (u16*)(p + 102400);
  u16*   b1b  = (u16*)(p + 104448);
  u16*   bf2b = (u16*)(p + 106496);
  u16*   bob  = (u16*)(p + 108544);
  const int* F = flags;

  // Overlay layout (peak 48.1 MiB; proven ws floor = 52.0 MiB):
  u16* ctx   = (u16*)(p + 131072);                     // [8192,1024]  16MiB
  u16* W1T   = ctx;                                    // after Wo: [4096,1024]
  u16* W2T   = ctx + (size_t)DFF * DM;                 //           [1024,4096]
  u16* qkv   = (u16*)(p + 131072 + 16777216);          // 2-batch q|k|v  24MiB
  u16* ao    = qkv;                                    // after attn: ao/x 16MiB
  u16* x     = qkv;
  u16* h     = qkv + (size_t)8192 * DM;                // FF scratch 16MiB
  unsigned int* maskb = (unsigned int*)(p + 131072 + 16777216 + 25165824); // 2MiB

  dim3 blk(256);
  const long SEC = (long)4096 * DM;                    // qkv section elems

  detect_kernel<<<1, 64, 0, stream>>>(query, flags);
  conv_params<<<16, blk, 0, stream>>>(g1, b1, bf2, bo, g1b, b1b, bf2b, bob, F);
  mask_pack<<<2048, blk, 0, stream>>>(mask, (unsigned long long*)maskb);
  s1t1_init<<<16, blk, 0, stream>>>(bf1, S1, T1, F);
  s1t1_acc<<<512, blk, 0, stream>>>(W1, gff, bff, S1, T1, F);

  for (int g = 0; g < 2; ++g) {
    const long aoff = (long)g * 4096 * DM;
    // QKV co-dispatch: z selects (query,Wq)/(key,Wk)/(value,Wv)
    gemm<128, 0, false, true, true><<<dim3(32 * 8, 3), blk, 0, stream>>>(
        query, keyi, value, aoff, Wq, Wk, Wv, nullptr,
        qkv, SEC, 4096, DM, DM, DM, nullptr, nullptr, nullptr, nullptr, F);
    attn_kernel<<<dim3(1024), blk, 0, stream>>>(
        qkv, qkv + SEC, qkv + 2 * SEC,
        maskb + (size_t)g * 2 * SEQ * 64, ctx + aoff);
  }

  // Wo projection, full M: ao overlays dead qkv
  gemm<128, 0, false, false, true><<<dim3(64 * 8, 1), blk, 0, stream>>>(
      ctx, ctx, ctx, 0, Wo, Wo, Wo, bob,
      ao, 0, 8192, DM, DM, DM, nullptr, nullptr, nullptr, nullptr, F);

  // x = LN(ao + query) in-place; LN2 stats saved
  ln_dual_v2<<<dim3(8192), blk, 0, stream>>>(ao, query, g1b, b1b, mu2, rs2, F);

  // ctx dead: build W1T (scaled by gff) and W2T in its place
  transpose_scale<<<dim3(DFF / 64, DM / 64), blk, 0, stream>>>(W1, W1T, DM, DFF, gff, F);
  transpose_scale<<<dim3(DM / 64, DFF / 64), blk, 0, stream>>>(W2, W2T, DFF, DM, nullptr, F);

  // FF quarters: h = relu(LN-folded x@W1g^T); z = h@W2T^T + bf2 + x (in-place)
  for (int q = 0; q < 4; ++q) {
    u16* xq = x + (long)q * 2048 * DM;
    gemm<128, 1, true, false, false><<<dim3(16 * 32, 1), blk, 0, stream>>>(
        xq, xq, xq, 0, W1T, W1T, W1T, nullptr,
        h, 0, 2048, DFF, DM, DFF, mu2 + q * 2048, rs2 + q * 2048, S1, T1, F);
    gemm<64, 2, false, false, false><<<dim3(32 * 8, 1), blk, 0, stream>>>(
        h, h, h, 0, W2T, W2T, W2T, bf2b,
        xq, 0, 2048, DM, DFF, DM, nullptr, nullptr, nullptr, nullptr, F);
  }

  ln_final2<<<dim3(8192), blk, 0, stream>>>(x, g2, b2, d_out, F);
}

// Round 7
// 1073.908 us; speedup vs baseline: 1.3739x; 1.0413x over previous
//
#include <hip/hip_runtime.h>

// ---------------------------------------------------------------------------
// SublayerConnection: MHA + residual/LN + FF + residual/LN
// B=4 S=2048 D=1024 H=16 Dk=64 Dff=4096. Inputs fp32-or-bf16 (runtime detect).
// Round 7: round-6 + (a) 2D super-tile L2 swizzle in all GEMMs (per-chunk
// A+B footprint < 4MiB XCD L2; fixes 135MB B re-fetch), (b) all-ones-mask
// wave-uniform fast path in attention.
// ---------------------------------------------------------------------------

#define DM   1024
#define DFF  4096
#define SEQ  2048

typedef unsigned short u16;
typedef short          sx8  __attribute__((ext_vector_type(8)));
typedef unsigned short ushx8 __attribute__((ext_vector_type(8)));
typedef unsigned short ushx4 __attribute__((ext_vector_type(4)));
typedef float          fx4  __attribute__((ext_vector_type(4)));
typedef unsigned int   uix4 __attribute__((ext_vector_type(4)));

__device__ __forceinline__ void async16(const void* g, void* l) {
  __builtin_amdgcn_global_load_lds((__attribute__((address_space(1))) void*)g,
                                   (__attribute__((address_space(3))) void*)l,
                                   16, 0, 0);
}
__device__ __forceinline__ float b2f(u16 u) {
  union { unsigned int i; float f; } v; v.i = ((unsigned int)u) << 16; return v.f;
}
__device__ __forceinline__ u16 f2b(float f) {
  union { float f; unsigned int i; } v; v.f = f;
  unsigned int r = v.i + 0x7fffu + ((v.i >> 16) & 1u);
  return (u16)(r >> 16);
}
__device__ __forceinline__ ushx8 ld8(const void* p, long idx, bool f32) {
  if (f32) {
    const float* s = (const float*)p + idx;
    fx4 a = *(const fx4*)s, b = *(const fx4*)(s + 4);
    ushx8 r;
    r[0] = f2b(a[0]); r[1] = f2b(a[1]); r[2] = f2b(a[2]); r[3] = f2b(a[3]);
    r[4] = f2b(b[0]); r[5] = f2b(b[1]); r[6] = f2b(b[2]); r[7] = f2b(b[3]);
    return r;
  }
  return *(const ushx8*)((const u16*)p + idx);
}
__device__ __forceinline__ void ld4f(const void* p, long idx, bool f32, float* o) {
  if (f32) {
    fx4 a = *(const fx4*)((const float*)p + idx);
    o[0] = a[0]; o[1] = a[1]; o[2] = a[2]; o[3] = a[3];
  } else {
    ushx4 a = *(const ushx4*)((const u16*)p + idx);
    o[0] = b2f(a[0]); o[1] = b2f(a[1]); o[2] = b2f(a[2]); o[3] = b2f(a[3]);
  }
}
__device__ __forceinline__ float ldf(const void* p, long idx, bool f32) {
  return f32 ? ((const float*)p)[idx] : b2f(((const u16*)p)[idx]);
}

// ---------------------------------------------------------------------------
__global__ void detect_kernel(const void* q, int* flags) {
  int lane = threadIdx.x;
  u16 v = ((const u16*)q)[lane << 1];
  int e = (v >> 7) & 0xff;
  int pl = (e >= 0x60 && e <= 0x8c) ? 1 : 0;
  unsigned long long m = __ballot(pl);
  if (lane == 0) { flags[0] = (__popcll(m) >= 40) ? 0 : 1; }
}

__global__ __launch_bounds__(256)
void conv_params(const void* g1, const void* b1, const void* bf2, const void* bo,
                 u16* g1b, u16* b1b, u16* bf2b, u16* bob, const int* f_p) {
  const bool f = (*f_p != 0);
  int i = blockIdx.x * 256 + threadIdx.x;   // 0..4095
  int which = i >> 10, j = i & 1023;
  const void* s = which == 0 ? g1 : (which == 1 ? b1 : (which == 2 ? bf2 : bo));
  u16* d = which == 0 ? g1b : (which == 1 ? b1b : (which == 2 ? bf2b : bob));
  d[j] = f2b(ldf(s, j, f));
}

// S1/T1: init then parallel accumulate.
__global__ __launch_bounds__(256)
void s1t1_init(const void* bf1, float* S1, float* T1, const int* f_p) {
  const bool f = (*f_p != 0);
  int n = blockIdx.x * 256 + threadIdx.x;
  S1[n] = 0.f;
  T1[n] = ldf(bf1, n, f);
}
__global__ __launch_bounds__(256)
void s1t1_acc(const void* W1, const void* gff, const void* bff,
              float* S1, float* T1, const int* f_p) {
  const bool f = (*f_p != 0);
  const int strip = blockIdx.x & 15;
  const int kc = blockIdx.x >> 4;
  const int n = (strip << 8) + threadIdx.x;
  const int k0 = kc << 5;
  float s = 0.f, t = 0.f;
#pragma unroll 4
  for (int k = k0; k < k0 + 32; ++k) {
    float w = ldf(W1, (long)k * DFF + n, f);
    s += ldf(gff, k, f) * w;
    t += ldf(bff, k, f) * w;
  }
  atomicAdd(&S1[n], s);
  atomicAdd(&T1[n], t);
}

// Pack mask into bits via ballot (2048 blocks x 4 waves x 32 words).
__global__ __launch_bounds__(256)
void mask_pack(const int* __restrict__ mask, unsigned long long* __restrict__ mb) {
  const int lane = threadIdx.x & 63, w = threadIdx.x >> 6;
  const long wave = (long)blockIdx.x * 4 + w;
#pragma unroll 4
  for (int i = 0; i < 32; ++i) {
    long p = wave * 32 + i;
    unsigned long long bm = __ballot(mask[(p << 6) + lane] != 0);
    if (lane == 0) mb[p] = bm;
  }
}

__global__ __launch_bounds__(256)
void transpose_scale(const void* __restrict__ in, u16* __restrict__ out,
                     int R, int C, const void* sc, const int* f_p) {
  __shared__ u16 tile[64][68];
  const bool f = (*f_p != 0);
  const int r0 = blockIdx.y << 6, c0 = blockIdx.x << 6;
  const int t = threadIdx.x;
#pragma unroll
  for (int it = 0; it < 4; ++it) {
    int j = (it << 8) + t;
    int rr = j >> 4, cc4 = (j & 15) << 2;
    float v[4];
    ld4f(in, (long)(r0 + rr) * C + c0 + cc4, f, v);
    float s = sc ? ldf(sc, r0 + rr, f) : 1.f;
#pragma unroll
    for (int q = 0; q < 4; ++q) tile[rr][cc4 + q] = f2b(v[q] * s);
  }
  __syncthreads();
#pragma unroll
  for (int it = 0; it < 4; ++it) {
    int j = (it << 8) + t;
    int cc = j >> 4, rr4 = (j & 15) << 2;
    ushx4 v;
    v[0] = tile[rr4 + 0][cc]; v[1] = tile[rr4 + 1][cc];
    v[2] = tile[rr4 + 2][cc]; v[3] = tile[rr4 + 3][cc];
    *(ushx4*)&out[(size_t)(c0 + cc) * R + r0 + rr4] = v;
  }
}

// ---------------------------------------------------------------------------
// Unified NT GEMM with 2D super-tile swizzle (cm x cn tiles per chunk; keeps
// per-chunk A+B < 4MiB so each XCD's L2 holds its working set).
// ---------------------------------------------------------------------------
template<int BM_, int EPI, bool RELU, bool AFLAG, bool BFLAG>
__global__ __launch_bounds__(256)
void gemm(const void* a0, const void* a1, const void* a2, long aoff,
          const void* b0, const void* b1, const void* b2,
          const u16* __restrict__ bias, u16* __restrict__ C, long csec,
          int M, int N, int K, int ldc, int cm, int cn,
          const float* __restrict__ mu2, const float* __restrict__ rs2,
          const float* __restrict__ S1, const float* __restrict__ T1,
          const int* f_p) {
  __shared__ __align__(16) u16 sA[BM_ * 64];
  __shared__ __align__(16) u16 sB[128 * 64];
  const int z = blockIdx.y;
  const void* A = z == 0 ? a0 : (z == 1 ? a1 : a2);
  const void* B = z == 0 ? b0 : (z == 1 ? b1 : b2);
  u16* Cz = C + (long)z * csec;
  const bool fl = (AFLAG || BFLAG) ? (*f_p != 0) : false;
  const int t = threadIdx.x;
  const int lane = t & 63, w = t >> 6;
  const int lm = lane & 15, lg = lane >> 4;

  // super-tile swizzle
  const int tm = M / BM_;
  const int bpc = cm * cn;
  const int chunk = blockIdx.x / bpc, wi = blockIdx.x % bpc;
  const int cpc = tm / cm;                       // chunks per m-column
  const int chm = chunk % cpc, chn = chunk / cpc;
  const int m0 = (chm * cm + (wi % cm)) * BM_;
  const int n0 = (chn * cn + (wi / cm)) << 7;

  constexpr int ITI = BM_ / 32;
  const int wm = (w & 1) * (BM_ / 2), wn = (w >> 1) << 6;

  fx4 acc[ITI][4];
#pragma unroll
  for (int i = 0; i < ITI; ++i)
#pragma unroll
    for (int j = 0; j < 4; ++j) acc[i][j] = (fx4){0.f, 0.f, 0.f, 0.f};

  for (int kt = 0; kt < K; kt += 64) {
    __syncthreads();
#pragma unroll
    for (int it = 0; it < BM_ / 32; ++it) {
      int ci = (it << 8) + t;
      int r = ci >> 3, cs = (ci & 7) ^ (r & 7);
      long gi = aoff + (long)(m0 + r) * K + kt + (cs << 3);
      if (AFLAG) { *(ushx8*)&sA[ci << 3] = ld8(A, gi, fl); }
      else       { async16(&((const u16*)A)[gi], &sA[ci << 3]); }
    }
#pragma unroll
    for (int it = 0; it < 4; ++it) {
      int ci = (it << 8) + t;
      int r = ci >> 3, cs = (ci & 7) ^ (r & 7);
      long gi = (long)(n0 + r) * K + kt + (cs << 3);
      if (BFLAG) { *(ushx8*)&sB[ci << 3] = ld8(B, gi, fl); }
      else       { async16(&((const u16*)B)[gi], &sB[ci << 3]); }
    }
    __syncthreads();
#pragma unroll
    for (int s = 0; s < 2; ++s) {
      const int g = (s << 2) + lg;
      sx8 afr[ITI], bfr[4];
#pragma unroll
      for (int i = 0; i < ITI; ++i) {
        int ra = wm + (i << 4) + lm;
        afr[i] = *(const sx8*)&sA[ra * 64 + ((g ^ (ra & 7)) << 3)];
      }
#pragma unroll
      for (int j = 0; j < 4; ++j) {
        int rb = wn + (j << 4) + lm;
        bfr[j] = *(const sx8*)&sB[rb * 64 + ((g ^ (rb & 7)) << 3)];
      }
#pragma unroll
      for (int i = 0; i < ITI; ++i)
#pragma unroll
        for (int j = 0; j < 4; ++j)
          acc[i][j] = __builtin_amdgcn_mfma_f32_16x16x32_bf16(afr[i], bfr[j], acc[i][j], 0, 0, 0);
    }
  }

#pragma unroll
  for (int j = 0; j < 4; ++j) {
    const int col = n0 + wn + (j << 4) + lm;
    float bv = 0.f, s1 = 0.f, t1 = 0.f;
    if (EPI == 0 || EPI == 2) { if (bias) bv = b2f(bias[col]); }
    if (EPI == 1) { s1 = S1[col]; t1 = T1[col]; }
#pragma unroll
    for (int i = 0; i < ITI; ++i) {
      const int row0 = m0 + wm + (i << 4) + (lg << 2);
#pragma unroll
      for (int r = 0; r < 4; ++r) {
        const int row = row0 + r;
        float v = acc[i][j][r];
        if (EPI == 0) v += bv;
        if (EPI == 1) {
          float rs = rs2[row], mu = mu2[row];
          v = rs * v - rs * mu * s1 + t1;
        }
        if (EPI == 2) v += bv + b2f(Cz[(size_t)row * ldc + col]);
        if (RELU) v = fmaxf(v, 0.f);
        Cz[(size_t)row * ldc + col] = f2b(v);
      }
    }
  }
}

// ---------------------------------------------------------------------------
// Flash attention, 2 batches per dispatch (grid 1024), packed-bit mask with
// all-ones wave-uniform fast path.
// ---------------------------------------------------------------------------
__global__ __launch_bounds__(256)
void attn_kernel(const u16* __restrict__ qsec, const u16* __restrict__ ksec,
                 const u16* __restrict__ vsec, const unsigned int* __restrict__ mb,
                 u16* __restrict__ ctx) {
  __shared__ __align__(16) u16 sQ[64 * 64];
  __shared__ __align__(16) u16 sK[128 * 64];
  __shared__ __align__(16) u16 sVt[64 * 136];
  __shared__ __align__(16) u16 sP[4][16 * 136];

  const int id = blockIdx.x;
  const int bl = id >> 9;
  const int h  = (id >> 5) & 15;
  const int q0 = (id & 31) << 6;
  const int t = threadIdx.x, lane = t & 63, w = t >> 6;
  const int hoff = h << 6;
  const int lm = lane & 15, lg = lane >> 4;
  const size_t bo = (size_t)bl * SEQ * DM;
  const u16* qp = qsec + bo;
  const u16* kp = ksec + bo;
  const u16* vp = vsec + bo;
  const unsigned int* mbb = mb + (size_t)bl * SEQ * 64;
  u16* cout = ctx + bo;

#pragma unroll
  for (int it = 0; it < 2; ++it) {
    int ci = (it << 8) + t;
    int r = ci >> 3, cs = (ci & 7) ^ (r & 7);
    ushx8 v = *(const ushx8*)&qp[((size_t)(q0 + r) << 10) + hoff + (cs << 3)];
    *(ushx8*)&sQ[ci << 3] = v;
  }

  fx4 o[4];
  float m_prev[4], lsum[4];
#pragma unroll
  for (int i = 0; i < 4; ++i) { o[i] = (fx4){0.f, 0.f, 0.f, 0.f}; m_prev[i] = -1e30f; lsum[i] = 0.f; }

  for (int kt = 0; kt < 16; ++kt) {
    const int k0 = kt << 7;
    __syncthreads();
#pragma unroll
    for (int it = 0; it < 4; ++it) {
      int ci = (it << 8) + t;
      int r = ci >> 3, cs = (ci & 7) ^ (r & 7);
      ushx8 v = *(const ushx8*)&kp[((size_t)(k0 + r) << 10) + hoff + (cs << 3)];
      *(ushx8*)&sK[ci << 3] = v;
    }
    {
      const int key = t >> 1;
#pragma unroll
      for (int it = 0; it < 4; ++it) {
        int dc = (t & 1) + (it << 1);
        ushx8 vv = *(const ushx8*)&vp[((size_t)(k0 + key) << 10) + hoff + (dc << 3)];
#pragma unroll
        for (int j = 0; j < 8; ++j)
          sVt[((dc << 3) + j) * 136 + key] = vv[j];
      }
    }
    __syncthreads();

    fx4 sc[8];
#pragma unroll
    for (int nt = 0; nt < 8; ++nt) sc[nt] = (fx4){0.f, 0.f, 0.f, 0.f};
#pragma unroll
    for (int s = 0; s < 2; ++s) {
      const int g = (s << 2) + lg;
      const int rowq = (w << 4) + lm;
      sx8 aq = *(const sx8*)&sQ[rowq * 64 + ((g ^ (rowq & 7)) << 3)];
#pragma unroll
      for (int nt = 0; nt < 8; ++nt) {
        int rk = (nt << 4) + lm;
        sx8 bk = *(const sx8*)&sK[rk * 64 + ((g ^ (rk & 7)) << 3)];
        sc[nt] = __builtin_amdgcn_mfma_f32_16x16x32_bf16(aq, bk, sc[nt], 0, 0, 0);
      }
    }

    // mask bits: per row r one uint4 covering cols [k0, k0+128)
    uix4 mw[4];
    unsigned int andall = 0xffffffffu;
#pragma unroll
    for (int r = 0; r < 4; ++r) {
      const int rowl = q0 + (w << 4) + (lg << 2) + r;
      mw[r] = *(const uix4*)&mbb[((size_t)rowl << 6) + (kt << 2)];
      andall &= mw[r][0] & mw[r][1] & mw[r][2] & mw[r][3];
    }

    float pmat[8][4];
    float tmax[4] = {-1e30f, -1e30f, -1e30f, -1e30f};
    if (__all(andall == 0xffffffffu)) {
      // fast path: no masked elements in this 64x128 tile
#pragma unroll
      for (int nt = 0; nt < 8; ++nt)
#pragma unroll
        for (int r = 0; r < 4; ++r) {
          float v = sc[nt][r] * 0.125f;
          pmat[nt][r] = v;
          tmax[r] = fmaxf(tmax[r], v);
        }
    } else {
#pragma unroll
      for (int nt = 0; nt < 8; ++nt)
#pragma unroll
        for (int r = 0; r < 4; ++r) {
          float v = sc[nt][r] * 0.125f;
          unsigned int bit = (mw[r][nt >> 1] >> (((nt & 1) << 4) + lm)) & 1u;
          if (!bit) v = -1e9f;
          pmat[nt][r] = v;
          tmax[r] = fmaxf(tmax[r], v);
        }
    }
#pragma unroll
    for (int r = 0; r < 4; ++r)
#pragma unroll
      for (int off = 1; off < 16; off <<= 1)
        tmax[r] = fmaxf(tmax[r], __shfl_xor(tmax[r], off));

    float alpha[4], rsum[4] = {0.f, 0.f, 0.f, 0.f};
#pragma unroll
    for (int r = 0; r < 4; ++r) {
      float mn = fmaxf(m_prev[r], tmax[r]);
      alpha[r] = __expf(m_prev[r] - mn);
      m_prev[r] = mn;
    }
#pragma unroll
    for (int nt = 0; nt < 8; ++nt)
#pragma unroll
      for (int r = 0; r < 4; ++r) {
        float pv = __expf(pmat[nt][r] - m_prev[r]);
        pmat[nt][r] = pv;
        rsum[r] += pv;
      }
#pragma unroll
    for (int r = 0; r < 4; ++r) {
#pragma unroll
      for (int off = 1; off < 16; off <<= 1)
        rsum[r] += __shfl_xor(rsum[r], off);
      lsum[r] = lsum[r] * alpha[r] + rsum[r];
    }
#pragma unroll
    for (int ot = 0; ot < 4; ++ot)
#pragma unroll
      for (int r = 0; r < 4; ++r)
        o[ot][r] *= alpha[r];

    u16* pw = &sP[w][0];
#pragma unroll
    for (int nt = 0; nt < 8; ++nt)
#pragma unroll
      for (int r = 0; r < 4; ++r)
        pw[((lg << 2) + r) * 136 + (nt << 4) + lm] = f2b(pmat[nt][r]);

#pragma unroll
    for (int ks = 0; ks < 4; ++ks) {
      sx8 ap = *(const sx8*)&pw[lm * 136 + (ks << 5) + (lg << 3)];
#pragma unroll
      for (int ot = 0; ot < 4; ++ot) {
        int d = (ot << 4) + lm;
        sx8 bv = *(const sx8*)&sVt[d * 136 + (ks << 5) + (lg << 3)];
        o[ot] = __builtin_amdgcn_mfma_f32_16x16x32_bf16(ap, bv, o[ot], 0, 0, 0);
      }
    }
  }

  float inv[4];
#pragma unroll
  for (int r = 0; r < 4; ++r) inv[r] = (lsum[r] > 0.f) ? 1.f / lsum[r] : 0.f;
#pragma unroll
  for (int ot = 0; ot < 4; ++ot)
#pragma unroll
    for (int r = 0; r < 4; ++r) {
      const int rowg = q0 + (w << 4) + (lg << 2) + r;
      const int col = hoff + (ot << 4) + lm;
      cout[((size_t)rowg << 10) + col] = f2b(o[ot][r] * inv[r]);
    }
}

// ---------------------------------------------------------------------------
__global__ __launch_bounds__(256)
void ln_dual_v2(u16* __restrict__ a, const void* __restrict__ res,
                const u16* __restrict__ g1b, const u16* __restrict__ b1b,
                float* __restrict__ mu2, float* __restrict__ rs2, const int* f_p) {
  __shared__ float red[8];
  const bool f = (*f_p != 0);
  const int row = blockIdx.x, t = threadIdx.x;
  const int lane = t & 63, w = t >> 6;
  const size_t base = (size_t)row << 10;
  const int c = t << 2;

  ushx4 a4 = *(const ushx4*)(a + base + c);
  float rv[4];
  ld4f(res, (long)base + c, f, rv);
  float v[4], s = 0.f, ss = 0.f;
#pragma unroll
  for (int j = 0; j < 4; ++j) { v[j] = b2f(a4[j]) + rv[j]; s += v[j]; ss += v[j] * v[j]; }
#pragma unroll
  for (int off = 32; off > 0; off >>= 1) { s += __shfl_xor(s, off); ss += __shfl_xor(ss, off); }
  if (lane == 0) { red[w] = s; red[4 + w] = ss; }
  __syncthreads();
  s = red[0] + red[1] + red[2] + red[3];
  ss = red[4] + red[5] + red[6] + red[7];
  float mu = s * (1.f / 1024.f);
  float rstd = rsqrtf(fmaxf(ss * (1.f / 1024.f) - mu * mu, 0.f) + 1e-5f);

  ushx4 g4 = *(const ushx4*)(g1b + c), b4 = *(const ushx4*)(b1b + c);
  float x[4], s2 = 0.f, ss2 = 0.f;
  ushx4 xo4;
#pragma unroll
  for (int j = 0; j < 4; ++j) {
    x[j] = (v[j] - mu) * rstd * b2f(g4[j]) + b2f(b4[j]);
    xo4[j] = f2b(x[j]);
    s2 += x[j]; ss2 += x[j] * x[j];
  }
  *(ushx4*)(a + base + c) = xo4;
#pragma unroll
  for (int off = 32; off > 0; off >>= 1) { s2 += __shfl_xor(s2, off); ss2 += __shfl_xor(ss2, off); }
  __syncthreads();
  if (lane == 0) { red[w] = s2; red[4 + w] = ss2; }
  __syncthreads();
  if (t == 0) {
    s2 = red[0] + red[1] + red[2] + red[3];
    ss2 = red[4] + red[5] + red[6] + red[7];
    float m2 = s2 * (1.f / 1024.f);
    mu2[row] = m2;
    rs2[row] = rsqrtf(fmaxf(ss2 * (1.f / 1024.f) - m2 * m2, 0.f) + 1e-5f);
  }
}

__global__ __launch_bounds__(256)
void ln_final2(const u16* __restrict__ z, const void* __restrict__ g,
               const void* __restrict__ bb, void* __restrict__ out, const int* f_p) {
  __shared__ float red[8];
  const bool f = (*f_p != 0);
  const int row = blockIdx.x, t = threadIdx.x;
  const int lane = t & 63, w = t >> 6;
  const size_t base = (size_t)row << 10;
  const int c = t << 2;

  ushx4 a4 = *(const ushx4*)(z + base + c);
  float v[4], s = 0.f, ss = 0.f;
#pragma unroll
  for (int j = 0; j < 4; ++j) { v[j] = b2f(a4[j]); s += v[j]; ss += v[j] * v[j]; }
#pragma unroll
  for (int off = 32; off > 0; off >>= 1) { s += __shfl_xor(s, off); ss += __shfl_xor(ss, off); }
  if (lane == 0) { red[w] = s; red[4 + w] = ss; }
  __syncthreads();
  s = red[0] + red[1] + red[2] + red[3];
  ss = red[4] + red[5] + red[6] + red[7];
  float mu = s * (1.f / 1024.f);
  float rstd = rsqrtf(fmaxf(ss * (1.f / 1024.f) - mu * mu, 0.f) + 1e-5f);

  float g4[4], b4[4];
  ld4f(g, c, f, g4); ld4f(bb, c, f, b4);
  if (f) {
    fx4 o4;
#pragma unroll
    for (int j = 0; j < 4; ++j) o4[j] = (v[j] - mu) * rstd * g4[j] + b4[j];
    *(fx4*)((float*)out + base + c) = o4;
  } else {
    ushx4 o4;
#pragma unroll
    for (int j = 0; j < 4; ++j) o4[j] = f2b((v[j] - mu) * rstd * g4[j] + b4[j]);
    *(ushx4*)((u16*)out + base + c) = o4;
  }
}

// ---------------------------------------------------------------------------
extern "C" void kernel_launch(void* const* d_in, const int* in_sizes, int n_in,
                              void* d_out, int out_size, void* d_ws, size_t ws_size,
                              hipStream_t stream) {
  (void)in_sizes; (void)n_in; (void)out_size; (void)ws_size;
  const void* query = d_in[0];
  const void* keyi  = d_in[1];
  const void* value = d_in[2];
  const int*  mask  = (const int*)d_in[3];
  const void* Wq = d_in[4];
  const void* Wk = d_in[5];
  const void* Wv = d_in[6];
  const void* Wo = d_in[7];
  const void* bo = d_in[8];
  const void* g1 = d_in[9];
  const void* b1 = d_in[10];
  const void* g2 = d_in[11];
  const void* b2 = d_in[12];
  const void* gff = d_in[13];
  const void* bff = d_in[14];
  const void* W1 = d_in[15];
  const void* bf1 = d_in[16];
  const void* W2 = d_in[17];
  const void* bf2 = d_in[18];

  char* p = (char*)d_ws;
  int*   flags = (int*)p;
  float* mu2  = (float*)(p + 4096);
  float* rs2  = (float*)(p + 4096 + 32768);
  float* S1   = (float*)(p + 4096 + 65536);
  float* T1   = (float*)(p + 4096 + 65536 + 16384);
  u16*   g1b  = (u16*)(p + 102400);
  u16*   b1b  = (u16*)(p + 104448);
  u16*   bf2b = (u16*)(p + 106496);
  u16*   bob  = (u16*)(p + 108544);
  const int* F = flags;

  u16* ctx   = (u16*)(p + 131072);                     // [8192,1024]  16MiB
  u16* W1T   = ctx;
  u16* W2T   = ctx + (size_t)DFF * DM;
  u16* qkv   = (u16*)(p + 131072 + 16777216);          // 24MiB
  u16* ao    = qkv;
  u16* x     = qkv;
  u16* h     = qkv + (size_t)8192 * DM;                // 16MiB (overlays v+maskb area post-attn)
  unsigned int* maskb = (unsigned int*)(p + 131072 + 16777216 + 25165824); // 2MiB

  dim3 blk(256);
  const long SEC = (long)4096 * DM;

  detect_kernel<<<1, 64, 0, stream>>>(query, flags);
  conv_params<<<16, blk, 0, stream>>>(g1, b1, bf2, bo, g1b, b1b, bf2b, bob, F);
  mask_pack<<<2048, blk, 0, stream>>>(mask, (unsigned long long*)maskb);
  s1t1_init<<<16, blk, 0, stream>>>(bf1, S1, T1, F);
  s1t1_acc<<<512, blk, 0, stream>>>(W1, gff, bff, S1, T1, F);

  for (int g = 0; g < 2; ++g) {
    const long aoff = (long)g * 4096 * DM;
    gemm<128, 0, false, true, true><<<dim3(32 * 8, 3), blk, 0, stream>>>(
        query, keyi, value, aoff, Wq, Wk, Wv, nullptr,
        qkv, SEC, 4096, DM, DM, DM, 4, 4, nullptr, nullptr, nullptr, nullptr, F);
    attn_kernel<<<dim3(1024), blk, 0, stream>>>(
        qkv, qkv + SEC, qkv + 2 * SEC,
        maskb + (size_t)g * 2 * SEQ * 64, ctx + aoff);
  }

  gemm<128, 0, false, false, true><<<dim3(64 * 8, 1), blk, 0, stream>>>(
      ctx, ctx, ctx, 0, Wo, Wo, Wo, bob,
      ao, 0, 8192, DM, DM, DM, 4, 4, nullptr, nullptr, nullptr, nullptr, F);

  ln_dual_v2<<<dim3(8192), blk, 0, stream>>>(ao, query, g1b, b1b, mu2, rs2, F);

  transpose_scale<<<dim3(DFF / 64, DM / 64), blk, 0, stream>>>(W1, W1T, DM, DFF, gff, F);
  transpose_scale<<<dim3(DM / 64, DFF / 64), blk, 0, stream>>>(W2, W2T, DFF, DM, nullptr, F);

  for (int q = 0; q < 4; ++q) {
    u16* xq = x + (long)q * 2048 * DM;
    gemm<128, 1, true, false, false><<<dim3(16 * 32, 1), blk, 0, stream>>>(
        xq, xq, xq, 0, W1T, W1T, W1T, nullptr,
        h, 0, 2048, DFF, DM, DFF, 4, 4, mu2 + q * 2048, rs2 + q * 2048, S1, T1, F);
    gemm<64, 2, false, false, false><<<dim3(32 * 8, 1), blk, 0, stream>>>(
        h, h, h, 0, W2T, W2T, W2T, bf2b,
        xq, 0, 2048, DM, DFF, DM, 2, 2, nullptr, nullptr, nullptr, nullptr, F);
  }

  ln_final2<<<dim3(8192), blk, 0, stream>>>(x, g2, b2, d_out, F);
}